// Round 5
// baseline (43.231 us; speedup 1.0000x reference)
//
#include <hip/hip_runtime.h>

typedef float  f32x4  __attribute__((ext_vector_type(4)));
typedef float  f32x4a __attribute__((ext_vector_type(4), aligned(4)));
typedef float  f32x2a __attribute__((ext_vector_type(2), aligned(4)));
typedef __bf16 bf16x8 __attribute__((ext_vector_type(8)));
typedef short  short8 __attribute__((ext_vector_type(8)));

#define F      65
#define NTT    17           // 16 D-tiles of 16 cols + 1 S-tile
#define KS3    3            // K padded (65 + bias) -> 96, 3 ksteps of 32
#define RPB    128          // rows per block (4 waves x 32 rows)

__device__ __forceinline__ float fast_sigmoid(float x) {
  float e = __builtin_amdgcn_exp2f(-1.4426950408889634f * x);
  return __builtin_amdgcn_rcpf(1.0f + e);
}
template<int CTRL>
__device__ __forceinline__ float dpp_mov(float v) {
  return __builtin_bit_cast(float,
    __builtin_amdgcn_update_dpp(0, __builtin_bit_cast(int, v), CTRL, 0xF, 0xF, true));
}
__device__ __forceinline__ float reduce16(float v) {
  v += dpp_mov<0xB1>(v);                   // xor1 (quad_perm)
  v += dpp_mov<0x4E>(v);                   // xor2 (quad_perm)
  v += dpp_mov<0x141>(v);                  // xor4 (row_half_mirror)
  v += dpp_mov<0x140>(v);                  // xor8 (row_mirror)
  return v;
}

// ---- prepass: fragment-ordered bf16 W blob (verified R4) -------------------
// chunk = (t*3+s)*64 + lane ; lane holds 8 bf16 of B:
//   col n = 16*t + (lane&15), k = 32*s + 8*(lane>>4) + j   (k==65 is bias row)
__global__ void prep_w(const float* __restrict__ W_S, const float* __restrict__ b_S,
                       const float* __restrict__ W_D, const float* __restrict__ b_D,
                       unsigned short* __restrict__ wsb) {
  int b = blockIdx.x;              // 0..50 = t*3+s
  int t = b / 3, s = b % 3;
  int l = threadIdx.x;
  int c = l & 15, q = l >> 4;
  short8 out;
#pragma unroll
  for (int j = 0; j < 8; ++j) {
    int k = 32 * s + 8 * q + j;
    float v = 0.0f;
    if (t < 16) {
      int n = 16 * t + c;
      if (k < F)       v = W_D[n * F + k];
      else if (k == F) v = b_D[n];
    } else if (c < 8) {
      if (k < F)       v = W_S[c * F + k];
      else if (k == F) v = b_S[c];
    }
    unsigned int u = __builtin_bit_cast(unsigned int, v);
    u += 0x7FFFu + ((u >> 16) & 1u);
    out[j] = (short)(u >> 16);
  }
  reinterpret_cast<short8*>(wsb)[b * 64 + l] = out;
}

// ---- Ml (bits 0-3 of d) + write Mt (bits 4-7, tile t = c) ------------------
__device__ __forceinline__ float ml_mt(float (*soutv)[9], float (*rowrec)[17],
                                       int R, int c) {
  f32x2a p01 = *reinterpret_cast<const f32x2a*>(&soutv[R][0]);
  f32x2a p23 = *reinterpret_cast<const f32x2a*>(&soutv[R][2]);
  f32x2a p45 = *reinterpret_cast<const f32x2a*>(&soutv[R][4]);
  f32x2a p67 = *reinterpret_cast<const f32x2a*>(&soutv[R][6]);
  float m = 0.99999f;
  m *= (c & 1) ? p01[0] : 1.0f - p01[0];
  m *= (c & 2) ? p01[1] : 1.0f - p01[1];
  m *= (c & 4) ? p23[0] : 1.0f - p23[0];
  m *= (c & 8) ? p23[1] : 1.0f - p23[1];
  float mt = (c & 1) ? p45[0] : 1.0f - p45[0];
  mt *= (c & 2) ? p45[1] : 1.0f - p45[1];
  mt *= (c & 4) ? p67[0] : 1.0f - p67[0];
  mt *= (c & 8) ? p67[1] : 1.0f - p67[1];
  rowrec[R][c] = mt;
  return m;
}

// ---- main fused kernel: no LDS blob, no barrier, B direct from L2 ----------
__launch_bounds__(256, 4)   // 4 waves/EU -> unified reg cap 128
__global__ void mpuf_main(const float* __restrict__ phi,
                          const unsigned short* __restrict__ wsb,
                          float* __restrict__ out_ans,
                          float* __restrict__ out_rel) {
  __shared__ float soutv[RPB][9];          // 4608 B
  __shared__ float rowrec[RPB][17];        // 8704 B

  const int tid  = threadIdx.x;
  const int wave = tid >> 6;
  const int l    = tid & 63;
  const int c    = l & 15;                 // col-in-tile / row-in-fragment
  const int q    = l >> 4;                 // k-group / C-row quad
  const int wrow = wave * 32;
  const int brow = blockIdx.x * RPB;

  const float* prow0 = phi + (size_t)(brow + wrow + c) * F;
  const float* prow1 = prow0 + (size_t)16 * F;

  // A loads: 8 x dwordx4 + 2 scalars, issued first (HBM latency)
  f32x4a f40[4], f41[4];
#pragma unroll
  for (int s = 0; s < 2; ++s) {
    f40[2 * s]     = *reinterpret_cast<const f32x4a*>(prow0 + 32 * s + 8 * q);
    f40[2 * s + 1] = *reinterpret_cast<const f32x4a*>(prow0 + 32 * s + 8 * q + 4);
    f41[2 * s]     = *reinterpret_cast<const f32x4a*>(prow1 + 32 * s + 8 * q);
    f41[2 * s + 1] = *reinterpret_cast<const f32x4a*>(prow1 + 32 * s + 8 * q + 4);
  }
  const float a640 = prow0[64];
  const float a641 = prow1[64];

  // B prefetch: S-tile (t=16) + tile-pair 0 (chunks are (t*3+s)*64+l)
  const short8* wsv = reinterpret_cast<const short8*>(wsb);
  short8 bS[3], bcur[6];
#pragma unroll
  for (int s = 0; s < 3; ++s) bS[s] = wsv[(16 * KS3 + s) * 64 + l];
#pragma unroll
  for (int i = 0; i < 6; ++i) bcur[i] = wsv[i * 64 + l];

  // A -> bf16 fragments (compiler emits v_cvt_pk_bf16_f32)
  bf16x8 af0[3], af1[3];
#pragma unroll
  for (int s = 0; s < 2; ++s) {
    bf16x8 v0, v1;
#pragma unroll
    for (int j = 0; j < 4; ++j) {
      v0[j]     = (__bf16)f40[2 * s][j];
      v0[j + 4] = (__bf16)f40[2 * s + 1][j];
      v1[j]     = (__bf16)f41[2 * s][j];
      v1[j + 4] = (__bf16)f41[2 * s + 1][j];
    }
    af0[s] = v0; af1[s] = v1;
  }
  {
    bf16x8 v0 = {}, v1 = {};
    if (q == 0) {
      v0[0] = (__bf16)a640; v0[1] = (__bf16)1.0f;   // k=64 + bias row
      v1[0] = (__bf16)a641; v1[1] = (__bf16)1.0f;
    }
    af0[2] = v0; af1[2] = v1;
  }

  // ---- S tile: Sdelta (bias folded) for both fragments ---------------------
  f32x4 aS0 = {}, aS1 = {};
#pragma unroll
  for (int s = 0; s < KS3; ++s) {
    bf16x8 b = __builtin_bit_cast(bf16x8, bS[s]);
    aS0 = __builtin_amdgcn_mfma_f32_16x16x32_bf16(af0[s], b, aS0, 0, 0, 0);
    aS1 = __builtin_amdgcn_mfma_f32_16x16x32_bf16(af1[s], b, aS1, 0, 0, 0);
  }
  // C layout 16x16: col = lane&15, row = (lane>>4)*4 + r
  if (c < 8) {
#pragma unroll
    for (int r = 0; r < 4; ++r) {
      const int R0 = wrow + q * 4 + r, R1 = R0 + 16;
      out_rel[(size_t)(brow + R0) * 8 + c] = fabsf(aS0[r]);
      out_rel[(size_t)(brow + R1) * 8 + c] = fabsf(aS1[r]);
      soutv[R0][c] = fast_sigmoid(aS0[r]);
      soutv[R1][c] = fast_sigmoid(aS1[r]);
    }
  }
  // same-wave LDS producer/consumer (rows wrow..wrow+31 all owned by this
  // wave) -> compiler orders via lgkmcnt, no barrier needed (R4-verified).

  float Ml0[4], Ml1[4];
#pragma unroll
  for (int r = 0; r < 4; ++r) {
    const int R0 = wrow + q * 4 + r;
    Ml0[r] = ml_mt(soutv, rowrec, R0, c);
    Ml1[r] = ml_mt(soutv, rowrec, R0 + 16, c);
  }

  float ans0[4] = {0, 0, 0, 0}, ans1[4] = {0, 0, 0, 0};

  // ---- D tile pairs with next-pair register prefetch -----------------------
#pragma unroll 1
  for (int tp = 0; tp < 8; ++tp) {
    f32x4 a00 = {}, a01 = {}, a10 = {}, a11 = {};
#pragma unroll
    for (int s = 0; s < KS3; ++s) {
      bf16x8 b0 = __builtin_bit_cast(bf16x8, bcur[s]);       // tile 2tp
      bf16x8 b1 = __builtin_bit_cast(bf16x8, bcur[3 + s]);   // tile 2tp+1
      a00 = __builtin_amdgcn_mfma_f32_16x16x32_bf16(af0[s], b0, a00, 0, 0, 0);
      a10 = __builtin_amdgcn_mfma_f32_16x16x32_bf16(af1[s], b0, a10, 0, 0, 0);
      a01 = __builtin_amdgcn_mfma_f32_16x16x32_bf16(af0[s], b1, a01, 0, 0, 0);
      a11 = __builtin_amdgcn_mfma_f32_16x16x32_bf16(af1[s], b1, a11, 0, 0, 0);
    }
    // prefetch next pair while MFMAs + epilogue run
    short8 bnxt[6];
    const int tpn = (tp < 7) ? tp + 1 : 7;
#pragma unroll
    for (int i = 0; i < 6; ++i) bnxt[i] = wsv[(tpn * 6 + i) * 64 + l];
#pragma unroll
    for (int r = 0; r < 4; ++r) {
      const int R0 = wrow + q * 4 + r, R1 = R0 + 16;
      f32x2a w0 = *reinterpret_cast<const f32x2a*>(&rowrec[R0][2 * tp]);
      f32x2a w1 = *reinterpret_cast<const f32x2a*>(&rowrec[R1][2 * tp]);
      ans0[r] = fmaf(fast_sigmoid(a00[r]), w0[0], ans0[r]);
      ans0[r] = fmaf(fast_sigmoid(a01[r]), w0[1], ans0[r]);
      ans1[r] = fmaf(fast_sigmoid(a10[r]), w1[0], ans1[r]);
      ans1[r] = fmaf(fast_sigmoid(a11[r]), w1[1], ans1[r]);
    }
#pragma unroll
    for (int i = 0; i < 6; ++i) bcur[i] = bnxt[i];
  }

  // ---- apply Ml, 16-lane DPP reduce, vectorized store ----------------------
#pragma unroll
  for (int r = 0; r < 4; ++r) {
    ans0[r] = reduce16(Ml0[r] * ans0[r]);
    ans1[r] = reduce16(Ml1[r] * ans1[r]);
  }
  if (c == 0) {
    f32x4 o0 = { ans0[0], ans0[1], ans0[2], ans0[3] };
    f32x4 o1 = { ans1[0], ans1[1], ans1[2], ans1[3] };
    *reinterpret_cast<f32x4*>(&out_ans[brow + wrow + q * 4])      = o0;
    *reinterpret_cast<f32x4*>(&out_ans[brow + wrow + 16 + q * 4]) = o1;
  }
}

extern "C" void kernel_launch(void* const* d_in, const int* in_sizes, int n_in,
                              void* d_out, int out_size, void* d_ws, size_t ws_size,
                              hipStream_t stream) {
  const float* phi = (const float*)d_in[0];
  const float* W_S = (const float*)d_in[1];
  const float* b_S = (const float*)d_in[2];
  const float* W_D = (const float*)d_in[3];
  const float* b_D = (const float*)d_in[4];
  const int rows = in_sizes[0] / F;        // 262144
  unsigned short* wsb = (unsigned short*)d_ws;   // 52224 B used
  float* out_ans = (float*)d_out;
  float* out_rel = out_ans + rows;
  hipLaunchKernelGGL(prep_w, dim3(NTT * KS3), dim3(64), 0, stream,
                     W_S, b_S, W_D, b_D, wsb);
  hipLaunchKernelGGL(mpuf_main, dim3(rows / RPB), dim3(256), 0, stream,
                     phi, wsb, out_ans, out_rel);
}

// Round 6
// 41.236 us; speedup vs baseline: 1.0484x; 1.0484x over previous
//
#include <hip/hip_runtime.h>

typedef float  f32x4  __attribute__((ext_vector_type(4)));
typedef float  f32x4a __attribute__((ext_vector_type(4), aligned(4)));
typedef float  f32x2a __attribute__((ext_vector_type(2), aligned(4)));
typedef __bf16 bf16x8 __attribute__((ext_vector_type(8)));
typedef short  short8 __attribute__((ext_vector_type(8)));

#define F      65
#define NTT    17           // 16 D-tiles of 16 cols + 1 S-tile
#define KS3    3            // K padded (65 + bias) -> 96, 3 ksteps of 32
#define RPB    128          // rows per block (4 waves x 32 rows)
#define NEGL2E -1.4426950408889634f

__device__ __forceinline__ float fast_sigmoid(float x) {
  float e = __builtin_amdgcn_exp2f(NEGL2E * x);
  return __builtin_amdgcn_rcpf(1.0f + e);
}
// for pre-scaled acc (acc = -log2e * delta): sigmoid = rcp(1 + exp2(acc))
__device__ __forceinline__ float sig_prescaled(float a) {
  return __builtin_amdgcn_rcpf(1.0f + __builtin_amdgcn_exp2f(a));
}
template<int CTRL>
__device__ __forceinline__ float dpp_mov(float v) {
  return __builtin_bit_cast(float,
    __builtin_amdgcn_update_dpp(0, __builtin_bit_cast(int, v), CTRL, 0xF, 0xF, true));
}
__device__ __forceinline__ float reduce16(float v) {
  v += dpp_mov<0xB1>(v);                   // xor1
  v += dpp_mov<0x4E>(v);                   // xor2
  v += dpp_mov<0x141>(v);                  // xor4 (row_half_mirror)
  v += dpp_mov<0x140>(v);                  // xor8 (row_mirror)
  return v;
}

// ---- prepass: fragment-ordered bf16 W blob; D-part pre-scaled by -log2e ----
// chunk = (t*3+s)*64 + lane ; lane holds 8 bf16 of B:
//   col n = 16*t + (lane&15), k = 32*s + 8*(lane>>4) + j   (k==65 is bias row)
__global__ void prep_w(const float* __restrict__ W_S, const float* __restrict__ b_S,
                       const float* __restrict__ W_D, const float* __restrict__ b_D,
                       unsigned short* __restrict__ wsb) {
  int b = blockIdx.x;              // 0..50 = t*3+s
  int t = b / 3, s = b % 3;
  int l = threadIdx.x;
  int c = l & 15, q = l >> 4;
  short8 out;
#pragma unroll
  for (int j = 0; j < 8; ++j) {
    int k = 32 * s + 8 * q + j;
    float v = 0.0f;
    if (t < 16) {
      int n = 16 * t + c;
      if (k < F)       v = NEGL2E * W_D[n * F + k];
      else if (k == F) v = NEGL2E * b_D[n];
    } else if (c < 8) {
      if (k < F)       v = W_S[c * F + k];
      else if (k == F) v = b_S[c];
    }
    unsigned int u = __builtin_bit_cast(unsigned int, v);
    u += 0x7FFFu + ((u >> 16) & 1u);
    out[j] = (short)(u >> 16);
  }
  reinterpret_cast<short8*>(wsb)[b * 64 + l] = out;
}

// ---- main fused kernel: no barrier, B direct from L1/L2, lean regs ---------
__launch_bounds__(256, 5)   // 5 waves/EU -> unified reg cap 102; live ~88
__global__ void mpuf_main(const float* __restrict__ phi,
                          const unsigned short* __restrict__ wsb,
                          float* __restrict__ out_ans,
                          float* __restrict__ out_rel) {
  __shared__ float soutv[RPB][9];          // 4.6 KB : f32 souts
  __shared__ float mtrec[RPB][17];         // 8.7 KB : Mt (bits 4-7) per (row, t=c)
  __shared__ float mlrec[RPB][17];         // 8.7 KB : Ml (bits 0-3) per (row, c)

  const int tid  = threadIdx.x;
  const int wave = tid >> 6;
  const int l    = tid & 63;
  const int c    = l & 15;                 // col-in-tile / row-in-A-fragment
  const int q    = l >> 4;                 // k-group / C-row quad
  const int wrow = wave * 32;
  const int brow = blockIdx.x * RPB;

  const float* prow0 = phi + (size_t)(brow + wrow + c) * F;
  const float* prow1 = prow0 + (size_t)16 * F;

  // A loads first (HBM latency)
  f32x4a f40[4], f41[4];
#pragma unroll
  for (int s = 0; s < 2; ++s) {
    f40[2 * s]     = *reinterpret_cast<const f32x4a*>(prow0 + 32 * s + 8 * q);
    f40[2 * s + 1] = *reinterpret_cast<const f32x4a*>(prow0 + 32 * s + 8 * q + 4);
    f41[2 * s]     = *reinterpret_cast<const f32x4a*>(prow1 + 32 * s + 8 * q);
    f41[2 * s + 1] = *reinterpret_cast<const f32x4a*>(prow1 + 32 * s + 8 * q + 4);
  }
  const float a640 = prow0[64];
  const float a641 = prow1[64];

  // B prefetch: S-tile (t=16) into bcur
  const short8* wsv = reinterpret_cast<const short8*>(wsb);
  short8 bcur[3], bnxt[3];
#pragma unroll
  for (int s = 0; s < 3; ++s) bcur[s] = wsv[(16 * KS3 + s) * 64 + l];
#pragma unroll
  for (int s = 0; s < 3; ++s) bnxt[s] = wsv[s * 64 + l];   // tile 0

  // A -> bf16 fragments
  bf16x8 af0[3], af1[3];
#pragma unroll
  for (int s = 0; s < 2; ++s) {
    bf16x8 v0, v1;
#pragma unroll
    for (int j = 0; j < 4; ++j) {
      v0[j]     = (__bf16)f40[2 * s][j];
      v0[j + 4] = (__bf16)f40[2 * s + 1][j];
      v1[j]     = (__bf16)f41[2 * s][j];
      v1[j + 4] = (__bf16)f41[2 * s + 1][j];
    }
    af0[s] = v0; af1[s] = v1;
  }
  {
    bf16x8 v0 = {}, v1 = {};
    if (q == 0) {
      v0[0] = (__bf16)a640; v0[1] = (__bf16)1.0f;
      v1[0] = (__bf16)a641; v1[1] = (__bf16)1.0f;
    }
    af0[2] = v0; af1[2] = v1;
  }

  // ---- S tile (unscaled): Sdelta with bias folded --------------------------
  f32x4 aS0 = {}, aS1 = {};
#pragma unroll
  for (int s = 0; s < KS3; ++s) {
    bf16x8 b = __builtin_bit_cast(bf16x8, bcur[s]);
    aS0 = __builtin_amdgcn_mfma_f32_16x16x32_bf16(af0[s], b, aS0, 0, 0, 0);
    aS1 = __builtin_amdgcn_mfma_f32_16x16x32_bf16(af1[s], b, aS1, 0, 0, 0);
  }
  // C layout 16x16: col = lane&15, row = (lane>>4)*4 + r
  if (c < 8) {
#pragma unroll
    for (int r = 0; r < 4; ++r) {
      const int R0 = wrow + q * 4 + r, R1 = R0 + 16;
      out_rel[(size_t)(brow + R0) * 8 + c] = fabsf(aS0[r]);
      out_rel[(size_t)(brow + R1) * 8 + c] = fabsf(aS1[r]);
      soutv[R0][c] = fast_sigmoid(aS0[r]);
      soutv[R1][c] = fast_sigmoid(aS1[r]);
    }
  }
  // same-wave LDS producer/consumer -> lgkmcnt-ordered, no barrier (verified).

  // ---- per-row records: Ml and Mt both into LDS (regs stay lean) -----------
#pragma unroll
  for (int rr = 0; rr < 8; ++rr) {
    const int R = wrow + (rr & 4) * 4 + q * 4 + (rr & 3);   // 8 rows per half
    f32x2a p01 = *reinterpret_cast<const f32x2a*>(&soutv[R][0]);
    f32x2a p23 = *reinterpret_cast<const f32x2a*>(&soutv[R][2]);
    f32x2a p45 = *reinterpret_cast<const f32x2a*>(&soutv[R][4]);
    f32x2a p67 = *reinterpret_cast<const f32x2a*>(&soutv[R][6]);
    float m = 0.99999f;
    m *= (c & 1) ? p01[0] : 1.0f - p01[0];
    m *= (c & 2) ? p01[1] : 1.0f - p01[1];
    m *= (c & 4) ? p23[0] : 1.0f - p23[0];
    m *= (c & 8) ? p23[1] : 1.0f - p23[1];
    mlrec[R][c] = m;
    float mt = (c & 1) ? p45[0] : 1.0f - p45[0];
    mt *= (c & 2) ? p45[1] : 1.0f - p45[1];
    mt *= (c & 4) ? p67[0] : 1.0f - p67[0];
    mt *= (c & 8) ? p67[1] : 1.0f - p67[1];
    mtrec[R][c] = mt;
  }

  float ans0[4] = {0, 0, 0, 0}, ans1[4] = {0, 0, 0, 0};

  // ---- D tiles, single-tile loop with register double-buffer ---------------
#pragma unroll 1
  for (int t = 0; t < 16; ++t) {
    f32x4 A0 = {}, A1 = {};
#pragma unroll
    for (int s = 0; s < KS3; ++s) {
      bf16x8 b = __builtin_bit_cast(bf16x8, bnxt[s]);
      A0 = __builtin_amdgcn_mfma_f32_16x16x32_bf16(af0[s], b, A0, 0, 0, 0);
      A1 = __builtin_amdgcn_mfma_f32_16x16x32_bf16(af1[s], b, A1, 0, 0, 0);
    }
    // prefetch next tile while MFMAs/epilogue in flight
    const int tn = (t < 15) ? t + 1 : 15;
#pragma unroll
    for (int s = 0; s < 3; ++s) bnxt[s] = wsv[(tn * KS3 + s) * 64 + l];
#pragma unroll
    for (int r = 0; r < 4; ++r) {
      const int R0 = wrow + q * 4 + r, R1 = R0 + 16;
      float w0 = mtrec[R0][t];             // broadcast per 16-lane group
      float w1 = mtrec[R1][t];
      ans0[r] = fmaf(sig_prescaled(A0[r]), w0, ans0[r]);
      ans1[r] = fmaf(sig_prescaled(A1[r]), w1, ans1[r]);
    }
  }

  // ---- apply Ml (from LDS), 16-lane DPP reduce, vectorized store -----------
#pragma unroll
  for (int r = 0; r < 4; ++r) {
    const int R0 = wrow + q * 4 + r, R1 = R0 + 16;
    ans0[r] = reduce16(mlrec[R0][c] * ans0[r]);
    ans1[r] = reduce16(mlrec[R1][c] * ans1[r]);
  }
  if (c == 0) {
    f32x4 o0 = { ans0[0], ans0[1], ans0[2], ans0[3] };
    f32x4 o1 = { ans1[0], ans1[1], ans1[2], ans1[3] };
    *reinterpret_cast<f32x4*>(&out_ans[brow + wrow + q * 4])      = o0;
    *reinterpret_cast<f32x4*>(&out_ans[brow + wrow + 16 + q * 4]) = o1;
  }
}

extern "C" void kernel_launch(void* const* d_in, const int* in_sizes, int n_in,
                              void* d_out, int out_size, void* d_ws, size_t ws_size,
                              hipStream_t stream) {
  const float* phi = (const float*)d_in[0];
  const float* W_S = (const float*)d_in[1];
  const float* b_S = (const float*)d_in[2];
  const float* W_D = (const float*)d_in[3];
  const float* b_D = (const float*)d_in[4];
  const int rows = in_sizes[0] / F;        // 262144
  unsigned short* wsb = (unsigned short*)d_ws;   // 52224 B used
  float* out_ans = (float*)d_out;
  float* out_rel = out_ans + rows;
  hipLaunchKernelGGL(prep_w, dim3(NTT * KS3), dim3(64), 0, stream,
                     W_S, b_S, W_D, b_D, wsb);
  hipLaunchKernelGGL(mpuf_main, dim3(rows / RPB), dim3(256), 0, stream,
                     phi, wsb, out_ans, out_rel);
}